// Round 8
// baseline (138.768 us; speedup 1.0000x reference)
//
#include <hip/hip_runtime.h>

// PointConv: B=4, N=16384, K=32, F=64
// out[p,f] = sum_k ( lrelu(rel(p,k) @ W1 + b1) @ W2 + b2 )[f] * x[idx[p,k], f]
//
// Round 12: three nulls (r10 VALU-cut, r11 LDS-hoist, both flat at ~70us)
// leave one latency class big enough for the measured ~2k stall cyc/point:
// HBM-class gather misses (FETCH 92MB vs 25MB compulsory -> x rows refetched
// ~4x, ~900cyc) with only ~1 body of cover, worsened by the compiler
// clamping to 128 VGPRs and sinking prefetches toward uses.
// Changes vs r10:
//  - xv TRIPLE buffer: x-gathers for point p issued 2 bodies ahead
//    (cover ~2 bodies > HBM latency)
//  - jm queue 3-deep (8 named ints, <=3 live), idx loaded 3 bodies ahead
//  - bodies fully unrolled (8 straight-line macro invocations, all buffer
//    rotation compile-time) + sched_barrier(0) at each body's load->compute
//    boundary so the scheduler cannot sink prefetch loads into the consumer
//  - r11 reg-hoists dropped (proven null) to pay for the 3rd xv buffer;
//    w1p/bfrag read from LDS per body (conflict-free b128, also proven null)
//  - epilogue FMA chain split 2-way for ILP
// Gating: WRITE_SIZE <= 25MB (spill tripwire). Live-set est ~195/256.
// If dur >= 65us: gather-latency theory dead -> pivot decomposition next.

#define NPTS   16384
#define KNB    32
#define F      64
#define BATCH  4
#define LOG2N  14
#define WPTS   8

typedef _Float16 h2     __attribute__((ext_vector_type(2)));
typedef _Float16 h8     __attribute__((ext_vector_type(8)));
typedef float    f32x16 __attribute__((ext_vector_type(16)));

__global__ __launch_bounds__(256, 2) void pointconv_mfma(
    const float* __restrict__ x,
    const float* __restrict__ pos,
    const int*   __restrict__ idx,
    const float* __restrict__ W1,
    const float* __restrict__ b1,
    const float* __restrict__ W2,
    const float* __restrict__ b2,
    float*       __restrict__ out)
{
    // w1p[g/2] = {wx,wx', wy,wy', wz,wz', b1,b1'} for g-pair (f16)
    __shared__ __align__(16) _Float16 w1p[32][8];
    // w2f[hf][t][c][m][j] = f16(W2[16t+8hf+j][2m+c]) — fragment-ordered,
    // lanes read consecutive 16B blocks -> conflict-free ds_read_b128
    __shared__ __align__(16) _Float16 w2f[2][4][2][32][8];

    const int tid = threadIdx.x;
    if (tid < 32) {
        const int g = 2 * tid;
        w1p[tid][0] = (_Float16)W1[0 * F + g]; w1p[tid][1] = (_Float16)W1[0 * F + g + 1];
        w1p[tid][2] = (_Float16)W1[1 * F + g]; w1p[tid][3] = (_Float16)W1[1 * F + g + 1];
        w1p[tid][4] = (_Float16)W1[2 * F + g]; w1p[tid][5] = (_Float16)W1[2 * F + g + 1];
        w1p[tid][6] = (_Float16)b1[g];         w1p[tid][7] = (_Float16)b1[g + 1];
    }
#pragma unroll
    for (int r = 0; r < 16; ++r) {             // 4096 elems, coalesced global read
        const int e = r * 256 + tid;           // e = g*64 + f
        const int g = e >> 6, f = e & 63;
        w2f[(g >> 3) & 1][g >> 4][f & 1][f >> 1][g & 7] = (_Float16)W2[e];
    }
    __syncthreads();

    const int lane = tid & 63;
    const int wv   = tid >> 6;
    const int m    = lane & 31;   // MFMA row (neighbor slot) / f-pair index
    const int hf   = lane >> 5;   // k-half of A/B fragments
    const int voff = hf << 4;     // bpermute byte base (source lane 4*hf + rA)

    const float2 b2v = *(const float2*)(b2 + 2 * m);

    const int p0   = (blockIdx.x * 4 + wv) * WPTS;
    const int p0_s = __builtin_amdgcn_readfirstlane(p0);
    const int base = (p0_s >> LOG2N) << LOG2N;                     // b*N
    const uint32_t m2 = 2u * (uint32_t)m;                          // f-pair offset

    const h2 c01 = { (_Float16)0.1f, (_Float16)0.1f };

    // rotating state: xv triple (96 regs), rl double (12), jm queue (<=3 live)
    float2 xv0[16], xv1[16], xv2[16];
    float  rl0[6], rl1[6];
    int jm0, jm1, jm2, jm3, jm4, jm5, jm6, jm7;

#define LOAD_JM(P)  idx[(uint32_t)((P) * KNB) + (uint32_t)m]

#define POSLOAD(RL, JM, P) {                                                  \
        const uint32_t nr3 = 3u * (uint32_t)(base + (JM));                    \
        const uint32_t pp3 = 3u * (uint32_t)(P);                              \
        RL[0] = pos[nr3];     RL[1] = pos[nr3 + 1]; RL[2] = pos[nr3 + 2];     \
        RL[3] = pos[pp3];     RL[4] = pos[pp3 + 1]; RL[5] = pos[pp3 + 2];     \
    }

#define GATHER(XV, JM) {                                                      \
        _Pragma("unroll")                                                     \
        for (int reg = 0; reg < 16; ++reg) {                                  \
            const int rA = (reg & 3) + ((reg >> 2) << 3);                     \
            const int jk = __builtin_amdgcn_ds_bpermute(voff + 4 * rA, (JM)); \
            const uint32_t xo = ((uint32_t)(base + jk) << 6) + m2;            \
            XV[reg] = *(const float2*)(x + xo);                               \
        }                                                                     \
    }

    // ---- prologue: jm for points 0..2, pos for point 0, xv for points 0,1 --
    jm0 = LOAD_JM(p0_s);
    jm1 = LOAD_JM(p0_s + 1);
    jm2 = LOAD_JM(p0_s + 2);
    POSLOAD(rl0, jm0, p0_s);
    GATHER(xv0, jm0);
    GATHER(xv1, jm1);

    // Body I (point p = p0+I):
    //   load jm[I+3]; pos for point I+1 (jm 2-body-old); gather xv for point
    //   I+2 (jm 1-body-old, consumed 2 bodies later); barrier; MFMA+epilogue.
#define BODY(I, XVcur, XVg, RLcur, RLnxt, JMpos, JMg, JMnew) {                \
        const int p_s = p0_s + (I);                                           \
        if ((I) + 3 < WPTS) JMnew = LOAD_JM(p_s + 3);                         \
        if ((I) + 1 < WPTS) POSLOAD(RLnxt, JMpos, p_s + 1);                   \
        if ((I) + 2 < WPTS) GATHER(XVg, JMg);                                 \
        __builtin_amdgcn_sched_barrier(0);                                    \
        /* MFMA phase (rl loaded 1 body ago) */                               \
        const float rx = RLcur[3] - RLcur[0];                                 \
        const float ry = RLcur[4] - RLcur[1];                                 \
        const float rz = RLcur[5] - RLcur[2];                                 \
        f32x16 acc0, acc1;                                                    \
        _Pragma("unroll")                                                     \
        for (int r = 0; r < 16; ++r) { acc0[r] = b2v.x; acc1[r] = b2v.y; }    \
        const h2 rxp = { (_Float16)rx, (_Float16)rx };                        \
        const h2 ryp = { (_Float16)ry, (_Float16)ry };                        \
        const h2 rzp = { (_Float16)rz, (_Float16)rz };                        \
        _Pragma("unroll")                                                     \
        for (int t = 0; t < 4; ++t) {                                         \
            h8 af;                                                            \
            _Pragma("unroll")                                                 \
            for (int jj = 0; jj < 4; ++jj) {                                  \
                const h8 w = *(const h8*)&w1p[8 * t + 4 * hf + jj][0];        \
                const h2 wx = __builtin_shufflevector(w, w, 0, 1);            \
                const h2 wy = __builtin_shufflevector(w, w, 2, 3);            \
                const h2 wz = __builtin_shufflevector(w, w, 4, 5);            \
                const h2 bb = __builtin_shufflevector(w, w, 6, 7);            \
                h2 hv = bb + rxp * wx;                                        \
                hv = hv + ryp * wy;                                           \
                hv = hv + rzp * wz;                                           \
                hv = __builtin_elementwise_max(hv, hv * c01);                 \
                af[2 * jj]     = hv[0];                                       \
                af[2 * jj + 1] = hv[1];                                       \
            }                                                                 \
            const h8 bf0 = *(const h8*)&w2f[hf][t][0][m][0];                  \
            const h8 bf1 = *(const h8*)&w2f[hf][t][1][m][0];                  \
            acc0 = __builtin_amdgcn_mfma_f32_32x32x16_f16(af, bf0, acc0, 0, 0, 0); \
            acc1 = __builtin_amdgcn_mfma_f32_32x32x16_f16(af, bf1, acc1, 0, 0, 0); \
        }                                                                     \
        /* epilogue: consume XVcur (gathered 2 bodies ago), 2-way ILP */      \
        float s0a = 0.f, s0b = 0.f, s1a = 0.f, s1b = 0.f;                     \
        _Pragma("unroll")                                                     \
        for (int reg = 0; reg < 16; reg += 2) {                               \
            s0a = fmaf(acc0[reg],     XVcur[reg].x,     s0a);                 \
            s0b = fmaf(acc0[reg + 1], XVcur[reg + 1].x, s0b);                 \
            s1a = fmaf(acc1[reg],     XVcur[reg].y,     s1a);                 \
            s1b = fmaf(acc1[reg + 1], XVcur[reg + 1].y, s1b);                 \
        }                                                                     \
        float s0 = s0a + s0b, s1 = s1a + s1b;                                 \
        s0 += __shfl_xor(s0, 32);                                             \
        s1 += __shfl_xor(s1, 32);                                             \
        if (hf == 0)                                                          \
            *(float2*)(out + (uint32_t)(p_s * F) + m2) = make_float2(s0, s1); \
    }

    // rotation: point p consumes xv_{p%3}, rl_{p&1}; body I gathers for
    // point I+2 into xv_{(I+2)%3} via jm_{I+2}; pos for I+1 via jm_{I+1}.
    BODY(0, xv0, xv2, rl0, rl1, jm1, jm2, jm3)
    BODY(1, xv1, xv0, rl1, rl0, jm2, jm3, jm4)
    BODY(2, xv2, xv1, rl0, rl1, jm3, jm4, jm5)
    BODY(3, xv0, xv2, rl1, rl0, jm4, jm5, jm6)
    BODY(4, xv1, xv0, rl0, rl1, jm5, jm6, jm7)
    BODY(5, xv2, xv1, rl1, rl0, jm6, jm7, jm0)   // JMnew guarded off
    BODY(6, xv0, xv2, rl0, rl1, jm7, jm0, jm0)   // GATHER guarded off
    BODY(7, xv1, xv0, rl1, rl0, jm0, jm0, jm0)   // loads all guarded off

#undef BODY
#undef GATHER
#undef POSLOAD
#undef LOAD_JM
}

extern "C" void kernel_launch(void* const* d_in, const int* in_sizes, int n_in,
                              void* d_out, int out_size, void* d_ws, size_t ws_size,
                              hipStream_t stream) {
    const float* x   = (const float*)d_in[0];
    const float* pos = (const float*)d_in[1];
    const int*   idx = (const int*)  d_in[2];
    const float* W1  = (const float*)d_in[3];
    const float* b1  = (const float*)d_in[4];
    const float* W2  = (const float*)d_in[5];
    const float* b2  = (const float*)d_in[6];
    float* out = (float*)d_out;

    dim3 grid((BATCH * NPTS) / (4 * WPTS));   // 4 waves/block, WPTS points/wave
    dim3 block(256);
    pointconv_mfma<<<grid, block, 0, stream>>>(x, pos, idx, W1, b1, W2, b2, out);
}